// Round 1
// baseline (264.846 us; speedup 1.0000x reference)
//
#include <hip/hip_runtime.h>

#define DM 256
#define SEQ 4096

typedef __attribute__((ext_vector_type(8))) short bf16x8;
typedef __attribute__((ext_vector_type(4))) float f32x4;

#define MFMA16(a, b, c) __builtin_amdgcn_mfma_f32_16x16x32_bf16(a, b, c, 0, 0, 0)

__device__ __forceinline__ short f2bf(float f) {
    union { float f; unsigned u; } c; c.f = f;
    unsigned r = (c.u + 0x7FFFu + ((c.u >> 16) & 1u)) >> 16;   // RNE
    return (short)r;
}
__device__ __forceinline__ float bf2f(short s) {
    union { unsigned u; float f; } c; c.u = ((unsigned)(unsigned short)s) << 16; return c.f;
}
__device__ __forceinline__ bf16x8 pack8(float4 a, float4 b) {
    bf16x8 r;
    r[0] = f2bf(a.x); r[1] = f2bf(a.y); r[2] = f2bf(a.z); r[3] = f2bf(a.w);
    r[4] = f2bf(b.x); r[5] = f2bf(b.y); r[6] = f2bf(b.z); r[7] = f2bf(b.w);
    return r;
}

// ---------------- weight f32 -> bf16 conversion ----------------
// layout in ws (shorts): wq@0 wk@65536 wv@131072 wm@196608 w1@262144 w2@393216
__global__ __launch_bounds__(256) void kWconv(const float* __restrict__ wq, const float* __restrict__ wk,
                                              const float* __restrict__ wv, const float* __restrict__ wm,
                                              const float* __restrict__ w1, const float* __restrict__ w2,
                                              short* __restrict__ dstws) {
    int blk = blockIdx.x;
    const float* src; short* dst;
    if (blk < 32)       { src = wq; dst = dstws;          }
    else if (blk < 64)  { src = wk; dst = dstws + 65536;  blk -= 32; }
    else if (blk < 96)  { src = wv; dst = dstws + 131072; blk -= 64; }
    else if (blk < 128) { src = wm; dst = dstws + 196608; blk -= 96; }
    else if (blk < 192) { src = w1; dst = dstws + 262144; blk -= 128; }
    else                { src = w2; dst = dstws + 393216; blk -= 192; }
    int idx = (blk * 256 + threadIdx.x) * 8;
    float4 f0 = *(const float4*)(src + idx), f1 = *(const float4*)(src + idx + 4);
    *(bf16x8*)(dst + idx) = pack8(f0, f1);
}

// ---------------- kernel A: K/V proj + KV, Ksum partials ----------------
// grid 512 = 8 batches x 64 blocks (64 source rows each). 256 thr = 4 waves.
// wave w owns feature cols [w*64, w*64+64) = heads 2w, 2w+1.
__global__ __launch_bounds__(256) void kA(const float* __restrict__ src,
                                          const short* __restrict__ wk, const short* __restrict__ wv,
                                          float* __restrict__ kv_part, float* __restrict__ ksum_part) {
    __shared__ char lds[65536];   // per wave 16KB: kT[64][64] bf16, vT[64][64] bf16 (row=feat, col=s)
    int t = threadIdx.x, lane = t & 63, w = t >> 6, r16 = lane & 15, g = lane >> 4;
    int b = blockIdx.x >> 6, blk = blockIdx.x & 63;
    const float* S = src + ((size_t)b * SEQ + blk * 64) * DM;
    char* kT = lds + w * 16384;
    char* vT = kT + 8192;
    f32x4 zz = {0.f, 0.f, 0.f, 0.f};
    f32x4 ak[4][4], av[4][4];
#pragma unroll
    for (int mi = 0; mi < 4; mi++)
#pragma unroll
        for (int ni = 0; ni < 4; ni++) { ak[mi][ni] = zz; av[mi][ni] = zz; }
#pragma unroll
    for (int kt = 0; kt < 8; kt++) {
        bf16x8 A[4], Bk[4], Bv[4];
#pragma unroll
        for (int mi = 0; mi < 4; mi++) {
            const float* p = S + (mi * 16 + r16) * DM + kt * 32 + g * 8;
            float4 f0 = *(const float4*)p, f1 = *(const float4*)(p + 4);
            A[mi] = pack8(f0, f1);
        }
#pragma unroll
        for (int ni = 0; ni < 4; ni++) {
            int n = w * 64 + ni * 16 + r16;
            Bk[ni] = *(const bf16x8*)(wk + n * DM + kt * 32 + g * 8);
            Bv[ni] = *(const bf16x8*)(wv + n * DM + kt * 32 + g * 8);
        }
#pragma unroll
        for (int mi = 0; mi < 4; mi++)
#pragma unroll
            for (int ni = 0; ni < 4; ni++) {
                ak[mi][ni] = MFMA16(A[mi], Bk[ni], ak[mi][ni]);
                av[mi][ni] = MFMA16(A[mi], Bv[ni], av[mi][ni]);
            }
    }
    // elu(k)+1, ksum partials, transposed LDS write (row=feat, stride 128B, swizzled)
    float ksp[4] = {0.f, 0.f, 0.f, 0.f};
#pragma unroll
    for (int mi = 0; mi < 4; mi++)
#pragma unroll
        for (int ni = 0; ni < 4; ni++)
#pragma unroll
            for (int j = 0; j < 4; j++) {
                float q = ak[mi][ni][j];
                float e = q > 0.f ? q + 1.f : __expf(q);
                ksp[ni] += e;
                int srow = mi * 16 + g * 4 + j, feat = ni * 16 + r16;
                int by = (feat * 128 + srow * 2) ^ ((feat & 7) << 4);
                *(short*)(kT + by) = f2bf(e);
                *(short*)(vT + by) = f2bf(av[mi][ni][j]);
            }
    __syncthreads();
    // KVT[v][d] = sum_s V[s][v] * K[s][d]
    f32x4 kv[2][2][2];
#pragma unroll
    for (int h = 0; h < 2; h++)
#pragma unroll
        for (int vi = 0; vi < 2; vi++)
#pragma unroll
            for (int di = 0; di < 2; di++) kv[h][vi][di] = zz;
#pragma unroll
    for (int h = 0; h < 2; h++)
#pragma unroll
        for (int st = 0; st < 2; st++) {
            bf16x8 Af[2], Bf[2];
#pragma unroll
            for (int vi = 0; vi < 2; vi++) {
                int row = h * 32 + vi * 16 + r16;
                Af[vi] = *(const bf16x8*)(vT + ((row * 128 + (st * 32 + g * 8) * 2) ^ ((row & 7) << 4)));
            }
#pragma unroll
            for (int di = 0; di < 2; di++) {
                int row = h * 32 + di * 16 + r16;
                Bf[di] = *(const bf16x8*)(kT + ((row * 128 + (st * 32 + g * 8) * 2) ^ ((row & 7) << 4)));
            }
#pragma unroll
            for (int vi = 0; vi < 2; vi++)
#pragma unroll
                for (int di = 0; di < 2; di++) kv[h][vi][di] = MFMA16(Af[vi], Bf[di], kv[h][vi][di]);
        }
    // store partials: kv_part[b][blk][head][v*32+d]
    float* kvp = kv_part + ((size_t)(b * 64 + blk) * 8 + w * 2) * 1024;
#pragma unroll
    for (int h = 0; h < 2; h++)
#pragma unroll
        for (int vi = 0; vi < 2; vi++)
#pragma unroll
            for (int di = 0; di < 2; di++)
#pragma unroll
                for (int j = 0; j < 4; j++) {
                    int v = vi * 16 + g * 4 + j, d = di * 16 + r16;
                    kvp[h * 1024 + v * 32 + d] = kv[h][vi][di][j];
                }
#pragma unroll
    for (int ni = 0; ni < 4; ni++) {
        ksp[ni] += __shfl_xor(ksp[ni], 16);
        ksp[ni] += __shfl_xor(ksp[ni], 32);
    }
    if (lane < 16) {
        float* kp = ksum_part + (size_t)(b * 64 + blk) * 256 + w * 64;
#pragma unroll
        for (int ni = 0; ni < 4; ni++) kp[ni * 16 + lane] = ksp[ni];
    }
}

// ---------------- kernel A2: reduce partials ----------------
__global__ __launch_bounds__(256) void kA2(const float* __restrict__ kv_part, const float* __restrict__ ksum_part,
                                           short* __restrict__ kvt_bf, float* __restrict__ ksum) {
    int bh = blockIdx.x, b = bh >> 3, h = bh & 7, t = threadIdx.x;
#pragma unroll
    for (int i = 0; i < 4; i++) {
        int e = t + i * 256;
        float s = 0.f;
        for (int blk = 0; blk < 64; blk++)
            s += kv_part[((size_t)(b * 64 + blk) * 8 + h) * 1024 + e];
        kvt_bf[(size_t)bh * 1024 + e] = f2bf(s);
    }
    if (t < 32) {
        float s = 0.f;
        for (int blk = 0; blk < 64; blk++)
            s += ksum_part[(size_t)(b * 64 + blk) * 256 + h * 32 + t];
        ksum[bh * 32 + t] = s;
    }
}

// ---------------- kernel B: Q proj + attend + merge + LN1 + residual ----------------
__global__ __launch_bounds__(256) void kB(const float* __restrict__ x,
                                          const short* __restrict__ wq_bf, const short* __restrict__ wm_bf,
                                          const short* __restrict__ kvt_bf, const float* __restrict__ ksum,
                                          const float* __restrict__ g1, const float* __restrict__ b1,
                                          short* __restrict__ x1_ws) {
    __shared__ char xt[32768];
    __shared__ char qa[32768];
    __shared__ float ksum_l[256];
    __shared__ float red[64][4][2];
    int t = threadIdx.x, lane = t & 63, w = t >> 6, r16 = lane & 15, g = lane >> 4;
    int b = blockIdx.x >> 6, lb = blockIdx.x & 63, l0 = lb * 64;
    const float* xb = x + ((size_t)b * SEQ + l0) * DM;
    {
        int c8 = t & 31, r0 = t >> 5;
#pragma unroll
        for (int i = 0; i < 8; i++) {
            int row = r0 + i * 8;
            const float* p = xb + row * DM + c8 * 8;
            float4 f0 = *(const float4*)p, f1 = *(const float4*)(p + 4);
            int by = (row * 512 + c8 * 16) ^ ((row & 7) << 4);
            *(bf16x8*)(xt + by) = pack8(f0, f1);
        }
        ksum_l[t] = ksum[b * 256 + t];
    }
    __syncthreads();
    f32x4 zz = {0.f, 0.f, 0.f, 0.f};
    // Q projection
    f32x4 acc[4][4];
#pragma unroll
    for (int mi = 0; mi < 4; mi++)
#pragma unroll
        for (int ni = 0; ni < 4; ni++) acc[mi][ni] = zz;
#pragma unroll
    for (int kt = 0; kt < 8; kt++) {
        bf16x8 A[4], Bf[4];
#pragma unroll
        for (int mi = 0; mi < 4; mi++) {
            int row = mi * 16 + r16;
            A[mi] = *(const bf16x8*)(xt + ((row * 512 + (kt * 32 + g * 8) * 2) ^ ((row & 7) << 4)));
        }
#pragma unroll
        for (int ni = 0; ni < 4; ni++)
            Bf[ni] = *(const bf16x8*)(wq_bf + (w * 64 + ni * 16 + r16) * DM + kt * 32 + g * 8);
#pragma unroll
        for (int mi = 0; mi < 4; mi++)
#pragma unroll
            for (int ni = 0; ni < 4; ni++) acc[mi][ni] = MFMA16(A[mi], Bf[ni], acc[mi][ni]);
    }
    // elu+1 and Z denominators
    float ks[2][2];
    ks[0][0] = ksum_l[(w * 2) * 32 + r16];     ks[0][1] = ksum_l[(w * 2) * 32 + 16 + r16];
    ks[1][0] = ksum_l[(w * 2 + 1) * 32 + r16]; ks[1][1] = ksum_l[(w * 2 + 1) * 32 + 16 + r16];
    float Zr[4][2][4];
#pragma unroll
    for (int mi = 0; mi < 4; mi++)
#pragma unroll
        for (int j = 0; j < 4; j++) {
#pragma unroll
            for (int ni = 0; ni < 4; ni++) {
                float q = acc[mi][ni][j];
                acc[mi][ni][j] = q > 0.f ? q + 1.f : __expf(q);
            }
            float d0 = acc[mi][0][j] * ks[0][0] + acc[mi][1][j] * ks[0][1];
            float d1 = acc[mi][2][j] * ks[1][0] + acc[mi][3][j] * ks[1][1];
#pragma unroll
            for (int m = 1; m < 16; m <<= 1) { d0 += __shfl_xor(d0, m); d1 += __shfl_xor(d1, m); }
            Zr[mi][0][j] = 1.f / (d0 + 1e-6f);
            Zr[mi][1][j] = 1.f / (d1 + 1e-6f);
        }
    // write Q (bf16, swizzled)
#pragma unroll
    for (int mi = 0; mi < 4; mi++)
#pragma unroll
        for (int ni = 0; ni < 4; ni++)
#pragma unroll
            for (int j = 0; j < 4; j++) {
                int row = mi * 16 + g * 4 + j, col = w * 64 + ni * 16 + r16;
                *(short*)(qa + ((row * 512 + col * 2) ^ ((row & 7) << 4))) = f2bf(acc[mi][ni][j]);
            }
    __syncthreads();
    // attend: per head (2 per wave), attended[l][v] = sum_d Q[l][d]*KV[d][v]
    f32x4 at[2][4][2];
#pragma unroll
    for (int h = 0; h < 2; h++)
#pragma unroll
        for (int mi = 0; mi < 4; mi++)
#pragma unroll
            for (int vi = 0; vi < 2; vi++) at[h][mi][vi] = zz;
#pragma unroll
    for (int h = 0; h < 2; h++) {
        int hh = w * 2 + h;
        bf16x8 A2[4], B2[2];
#pragma unroll
        for (int mi = 0; mi < 4; mi++) {
            int row = mi * 16 + r16, col = hh * 32 + g * 8;
            A2[mi] = *(const bf16x8*)(qa + ((row * 512 + col * 2) ^ ((row & 7) << 4)));
        }
        const short* kvb = kvt_bf + (size_t)(b * 8 + hh) * 1024;
#pragma unroll
        for (int vi = 0; vi < 2; vi++)
            B2[vi] = *(const bf16x8*)(kvb + (vi * 16 + r16) * 32 + g * 8);
#pragma unroll
        for (int mi = 0; mi < 4; mi++)
#pragma unroll
            for (int vi = 0; vi < 2; vi++) at[h][mi][vi] = MFMA16(A2[mi], B2[vi], at[h][mi][vi]);
    }
    __syncthreads();
    // scale by Z, write attended over qa (bf16, swizzled)
#pragma unroll
    for (int h = 0; h < 2; h++)
#pragma unroll
        for (int mi = 0; mi < 4; mi++)
#pragma unroll
            for (int vi = 0; vi < 2; vi++)
#pragma unroll
                for (int j = 0; j < 4; j++) {
                    int row = mi * 16 + g * 4 + j, col = (w * 2 + h) * 32 + vi * 16 + r16;
                    float val = at[h][mi][vi][j] * Zr[mi][h][j];
                    *(short*)(qa + ((row * 512 + col * 2) ^ ((row & 7) << 4))) = f2bf(val);
                }
    __syncthreads();
    // merge GEMM
    f32x4 am[4][4];
#pragma unroll
    for (int mi = 0; mi < 4; mi++)
#pragma unroll
        for (int ni = 0; ni < 4; ni++) am[mi][ni] = zz;
#pragma unroll
    for (int kt = 0; kt < 8; kt++) {
        bf16x8 A[4], Bf[4];
#pragma unroll
        for (int mi = 0; mi < 4; mi++) {
            int row = mi * 16 + r16;
            A[mi] = *(const bf16x8*)(qa + ((row * 512 + (kt * 32 + g * 8) * 2) ^ ((row & 7) << 4)));
        }
#pragma unroll
        for (int ni = 0; ni < 4; ni++)
            Bf[ni] = *(const bf16x8*)(wm_bf + (w * 64 + ni * 16 + r16) * DM + kt * 32 + g * 8);
#pragma unroll
        for (int mi = 0; mi < 4; mi++)
#pragma unroll
            for (int ni = 0; ni < 4; ni++) am[mi][ni] = MFMA16(A[mi], Bf[ni], am[mi][ni]);
    }
    // LN partials per row (this wave's 64 cols)
#pragma unroll
    for (int mi = 0; mi < 4; mi++)
#pragma unroll
        for (int j = 0; j < 4; j++) {
            float s = am[mi][0][j] + am[mi][1][j] + am[mi][2][j] + am[mi][3][j];
            float s2 = am[mi][0][j] * am[mi][0][j] + am[mi][1][j] * am[mi][1][j] +
                       am[mi][2][j] * am[mi][2][j] + am[mi][3][j] * am[mi][3][j];
#pragma unroll
            for (int m = 1; m < 16; m <<= 1) { s += __shfl_xor(s, m); s2 += __shfl_xor(s2, m); }
            if (r16 == 0) { int row = mi * 16 + g * 4 + j; red[row][w][0] = s; red[row][w][1] = s2; }
        }
    __syncthreads();
    // epilogue: x1 = x + LN(message); write bf16 to qa (plain layout)
    float g1v[4], b1v[4];
#pragma unroll
    for (int ni = 0; ni < 4; ni++) { int col = w * 64 + ni * 16 + r16; g1v[ni] = g1[col]; b1v[ni] = b1[col]; }
#pragma unroll
    for (int mi = 0; mi < 4; mi++)
#pragma unroll
        for (int j = 0; j < 4; j++) {
            int row = mi * 16 + g * 4 + j;
            float mu = (red[row][0][0] + red[row][1][0] + red[row][2][0] + red[row][3][0]) * (1.f / DM);
            float ex2 = (red[row][0][1] + red[row][1][1] + red[row][2][1] + red[row][3][1]) * (1.f / DM);
            float rstd = rsqrtf(ex2 - mu * mu + 1e-5f);
#pragma unroll
            for (int ni = 0; ni < 4; ni++) {
                int col = w * 64 + ni * 16 + r16;
                float xv = bf2f(*(const short*)(xt + ((row * 512 + col * 2) ^ ((row & 7) << 4))));
                float x1v = xv + (am[mi][ni][j] - mu) * rstd * g1v[ni] + b1v[ni];
                *(short*)(qa + row * 512 + col * 2) = f2bf(x1v);
            }
        }
    __syncthreads();
    short* xop = x1_ws + ((size_t)b * SEQ + l0) * DM;
#pragma unroll
    for (int i = 0; i < 8; i++) {
        int idx = t + i * 256, row = idx >> 5, c8 = idx & 31;
        *(bf16x8*)(xop + row * DM + c8 * 8) = *(const bf16x8*)(qa + row * 512 + c8 * 16);
    }
}

// ---------------- kernel C: MLP + LN2 + residual ----------------
__global__ __launch_bounds__(256) void kC(const short* __restrict__ x1_ws,
                                          const short* __restrict__ w1_bf, const short* __restrict__ w2_bf,
                                          const float* __restrict__ g2, const float* __restrict__ b2,
                                          float* __restrict__ out) {
    __shared__ char buf[65536];   // phase1: x1 bf16 [64][256] swz; phase2: h bf16 [64][512] swz; phase3: ln f32 [64][256]
    __shared__ float red[64][4][2];
    int t = threadIdx.x, lane = t & 63, w = t >> 6, r16 = lane & 15, g = lane >> 4;
    int b = blockIdx.x >> 6, lb = blockIdx.x & 63, l0 = lb * 64;
    const short* x1p = x1_ws + ((size_t)b * SEQ + l0) * DM;
#pragma unroll
    for (int i = 0; i < 8; i++) {
        int idx = t + i * 256, row = idx >> 5, c8 = idx & 31;
        bf16x8 v = *(const bf16x8*)(x1p + row * DM + c8 * 8);
        *(bf16x8*)(buf + ((row * 512 + c8 * 16) ^ ((row & 7) << 4))) = v;
    }
    __syncthreads();
    f32x4 zz = {0.f, 0.f, 0.f, 0.f};
    // GEMM1: h = relu(x1 @ w1^T), wave w -> cols [w*128, w*128+128)
    f32x4 a1[4][8];
#pragma unroll
    for (int mi = 0; mi < 4; mi++)
#pragma unroll
        for (int ni = 0; ni < 8; ni++) a1[mi][ni] = zz;
#pragma unroll
    for (int kt = 0; kt < 8; kt++) {
        bf16x8 A[4], Bf[8];
#pragma unroll
        for (int mi = 0; mi < 4; mi++) {
            int row = mi * 16 + r16;
            A[mi] = *(const bf16x8*)(buf + ((row * 512 + (kt * 32 + g * 8) * 2) ^ ((row & 7) << 4)));
        }
#pragma unroll
        for (int ni = 0; ni < 8; ni++)
            Bf[ni] = *(const bf16x8*)(w1_bf + (w * 128 + ni * 16 + r16) * DM + kt * 32 + g * 8);
#pragma unroll
        for (int mi = 0; mi < 4; mi++)
#pragma unroll
            for (int ni = 0; ni < 8; ni++) a1[mi][ni] = MFMA16(A[mi], Bf[ni], a1[mi][ni]);
    }
    __syncthreads();
    // relu + write h [64][512] bf16 swizzled
#pragma unroll
    for (int mi = 0; mi < 4; mi++)
#pragma unroll
        for (int ni = 0; ni < 8; ni++)
#pragma unroll
            for (int j = 0; j < 4; j++) {
                float hv = a1[mi][ni][j]; hv = hv > 0.f ? hv : 0.f;
                int row = mi * 16 + g * 4 + j, col = w * 128 + ni * 16 + r16;
                *(short*)(buf + ((row * 1024 + col * 2) ^ ((row & 7) << 4))) = f2bf(hv);
            }
    __syncthreads();
    // GEMM2: y = h @ w2^T (K=512), wave w -> cols [w*64, w*64+64)
    f32x4 a2[4][4];
#pragma unroll
    for (int mi = 0; mi < 4; mi++)
#pragma unroll
        for (int ni = 0; ni < 4; ni++) a2[mi][ni] = zz;
#pragma unroll
    for (int kt = 0; kt < 16; kt++) {
        bf16x8 A[4], Bf[4];
#pragma unroll
        for (int mi = 0; mi < 4; mi++) {
            int row = mi * 16 + r16;
            A[mi] = *(const bf16x8*)(buf + ((row * 1024 + (kt * 32 + g * 8) * 2) ^ ((row & 7) << 4)));
        }
#pragma unroll
        for (int ni = 0; ni < 4; ni++)
            Bf[ni] = *(const bf16x8*)(w2_bf + (w * 64 + ni * 16 + r16) * 512 + kt * 32 + g * 8);
#pragma unroll
        for (int mi = 0; mi < 4; mi++)
#pragma unroll
            for (int ni = 0; ni < 4; ni++) a2[mi][ni] = MFMA16(A[mi], Bf[ni], a2[mi][ni]);
    }
    // LN partials
#pragma unroll
    for (int mi = 0; mi < 4; mi++)
#pragma unroll
        for (int j = 0; j < 4; j++) {
            float s = a2[mi][0][j] + a2[mi][1][j] + a2[mi][2][j] + a2[mi][3][j];
            float s2 = a2[mi][0][j] * a2[mi][0][j] + a2[mi][1][j] * a2[mi][1][j] +
                       a2[mi][2][j] * a2[mi][2][j] + a2[mi][3][j] * a2[mi][3][j];
#pragma unroll
            for (int m = 1; m < 16; m <<= 1) { s += __shfl_xor(s, m); s2 += __shfl_xor(s2, m); }
            if (r16 == 0) { int row = mi * 16 + g * 4 + j; red[row][w][0] = s; red[row][w][1] = s2; }
        }
    __syncthreads();
    // LN -> f32 into buf (plain [64][256] f32)
    float g2v[4], b2v[4];
#pragma unroll
    for (int ni = 0; ni < 4; ni++) { int col = w * 64 + ni * 16 + r16; g2v[ni] = g2[col]; b2v[ni] = b2[col]; }
#pragma unroll
    for (int mi = 0; mi < 4; mi++)
#pragma unroll
        for (int j = 0; j < 4; j++) {
            int row = mi * 16 + g * 4 + j;
            float mu = (red[row][0][0] + red[row][1][0] + red[row][2][0] + red[row][3][0]) * (1.f / DM);
            float ex2 = (red[row][0][1] + red[row][1][1] + red[row][2][1] + red[row][3][1]) * (1.f / DM);
            float rstd = rsqrtf(ex2 - mu * mu + 1e-5f);
#pragma unroll
            for (int ni = 0; ni < 4; ni++) {
                int col = w * 64 + ni * 16 + r16;
                float ln = (a2[mi][ni][j] - mu) * rstd * g2v[ni] + b2v[ni];
                *(float*)(buf + row * 1024 + col * 4) = ln;
            }
        }
    __syncthreads();
    // out = x1 + ln (coalesced)
    float* op = out + ((size_t)b * SEQ + l0) * DM;
#pragma unroll
    for (int i = 0; i < 16; i++) {
        int idx = t + i * 256, row = idx >> 6, c4 = idx & 63;
        float4 f = *(const float4*)(buf + row * 1024 + c4 * 16);
        short4 xs = *(const short4*)(x1p + row * DM + c4 * 4);
        f.x += bf2f(xs.x); f.y += bf2f(xs.y); f.z += bf2f(xs.z); f.w += bf2f(xs.w);
        *(float4*)(op + row * DM + c4 * 4) = f;
    }
}

extern "C" void kernel_launch(void* const* d_in, const int* in_sizes, int n_in,
                              void* d_out, int out_size, void* d_ws, size_t ws_size,
                              hipStream_t stream) {
    const float* x   = (const float*)d_in[0];
    const float* src = (const float*)d_in[1];
    const float* wq  = (const float*)d_in[2];
    const float* wk  = (const float*)d_in[3];
    const float* wv  = (const float*)d_in[4];
    const float* wm  = (const float*)d_in[5];
    const float* w1  = (const float*)d_in[6];
    const float* w2  = (const float*)d_in[7];
    const float* g1  = (const float*)d_in[8];
    const float* b1  = (const float*)d_in[9];
    const float* g2  = (const float*)d_in[10];
    const float* b2  = (const float*)d_in[11];
    float* out = (float*)d_out;

    char* ws = (char*)d_ws;
    short* w_bf      = (short*)ws;                    // 524288 shorts = 1,048,576 B
    short* kvt_bf    = (short*)(ws + 1048576);        // 65536 shorts  =   131,072 B
    float* ksum      = (float*)(ws + 1179648);        // 2048 f32      =     8,192 B
    short* x1_ws     = (short*)(ws + 1187840);        // 8,388,608 shorts = 16,777,216 B
    float* kv_part   = (float*)(ws + 17965056);       // 4,194,304 f32 = 16,777,216 B
    float* ksum_part = (float*)(ws + 34742272);       // 131,072 f32   =    524,288 B
    // total 35,266,560 B

    kWconv<<<256, 256, 0, stream>>>(wq, wk, wv, wm, w1, w2, w_bf);
    kA<<<512, 256, 0, stream>>>(src, w_bf + 65536, w_bf + 131072, kv_part, ksum_part);
    kA2<<<64, 256, 0, stream>>>(kv_part, ksum_part, kvt_bf, ksum);
    kB<<<512, 256, 0, stream>>>(x, w_bf, w_bf + 196608, kvt_bf, ksum, g1, b1, x1_ws);
    kC<<<512, 256, 0, stream>>>(x1_ws, w_bf + 262144, w_bf + 393216, g2, b2, out);
}

// Round 2
// 247.729 us; speedup vs baseline: 1.0691x; 1.0691x over previous
//
#include <hip/hip_runtime.h>

#define DM 256
#define SEQ 4096

typedef __attribute__((ext_vector_type(8))) short bf16x8;
typedef __attribute__((ext_vector_type(4))) float f32x4;

#define MFMA16(a, b, c) __builtin_amdgcn_mfma_f32_16x16x32_bf16(a, b, c, 0, 0, 0)

__device__ __forceinline__ short f2bf(float f) {
    union { float f; unsigned u; } c; c.f = f;
    unsigned r = (c.u + 0x7FFFu + ((c.u >> 16) & 1u)) >> 16;   // RNE
    return (short)r;
}
__device__ __forceinline__ float bf2f(short s) {
    union { unsigned u; float f; } c; c.u = ((unsigned)(unsigned short)s) << 16; return c.f;
}
__device__ __forceinline__ bf16x8 pack8(float4 a, float4 b) {
    bf16x8 r;
    r[0] = f2bf(a.x); r[1] = f2bf(a.y); r[2] = f2bf(a.z); r[3] = f2bf(a.w);
    r[4] = f2bf(b.x); r[5] = f2bf(b.y); r[6] = f2bf(b.z); r[7] = f2bf(b.w);
    return r;
}

// ---------------- weight f32 -> bf16 ----------------
// ws shorts: wq@0 wk@65536 wv@131072 wm@196608 w1@262144 w2@393216
__global__ __launch_bounds__(256) void kWconv(const float* __restrict__ wq, const float* __restrict__ wk,
                                              const float* __restrict__ wv, const float* __restrict__ wm,
                                              const float* __restrict__ w1, const float* __restrict__ w2,
                                              short* __restrict__ dstws) {
    int blk = blockIdx.x;
    const float* src; short* dst;
    if (blk < 32)       { src = wq; dst = dstws;          }
    else if (blk < 64)  { src = wk; dst = dstws + 65536;  blk -= 32; }
    else if (blk < 96)  { src = wv; dst = dstws + 131072; blk -= 64; }
    else if (blk < 128) { src = wm; dst = dstws + 196608; blk -= 96; }
    else if (blk < 192) { src = w1; dst = dstws + 262144; blk -= 128; }
    else                { src = w2; dst = dstws + 393216; blk -= 192; }
    int idx = (blk * 256 + threadIdx.x) * 8;
    float4 f0 = *(const float4*)(src + idx), f1 = *(const float4*)(src + idx + 4);
    *(bf16x8*)(dst + idx) = pack8(f0, f1);
}

// ---------------- kernel A: K/V proj + KV, Ksum partials ----------------
// grid 512 = 8 b x 64 blocks (64 src rows). 512 thr = 8 waves; wave w = head w (32 cols).
__global__ __launch_bounds__(512, 4) void kA(const float* __restrict__ src,
                                             const short* __restrict__ wk, const short* __restrict__ wv,
                                             float* __restrict__ kv_part, float* __restrict__ ksum_part) {
    __shared__ char lds[65536];   // phase1: xs[64][256] bf16 swz (32KB); phase2: per-wave kT/vT 8KB
    int t = threadIdx.x, lane = t & 63, w = t >> 6, r16 = lane & 15, g = lane >> 4;
    int b = blockIdx.x >> 6, blk = blockIdx.x & 63;
    const float* S = src + ((size_t)b * SEQ + blk * 64) * DM;
    // stage source tile f32->bf16 swizzled (all 64 rows x 256 cols)
#pragma unroll
    for (int i = 0; i < 4; i++) {
        int chunk = t + i * 512, row = chunk >> 5, c8 = chunk & 31;
        const float* p = S + row * DM + c8 * 8;
        float4 f0 = *(const float4*)p, f1 = *(const float4*)(p + 4);
        int by = (row * 512 + c8 * 16) ^ ((row & 7) << 4);
        *(bf16x8*)(lds + by) = pack8(f0, f1);
    }
    __syncthreads();
    f32x4 zz = {0.f, 0.f, 0.f, 0.f};
    f32x4 ak[4][2], av[4][2];
#pragma unroll
    for (int mi = 0; mi < 4; mi++)
#pragma unroll
        for (int ni = 0; ni < 2; ni++) { ak[mi][ni] = zz; av[mi][ni] = zz; }
#pragma unroll
    for (int kt = 0; kt < 8; kt++) {
        bf16x8 A[4];
#pragma unroll
        for (int mi = 0; mi < 4; mi++) {
            int row = mi * 16 + r16;
            A[mi] = *(const bf16x8*)(lds + ((row * 512 + (kt * 32 + g * 8) * 2) ^ ((row & 7) << 4)));
        }
#pragma unroll
        for (int ni = 0; ni < 2; ni++) {
            int n = w * 32 + ni * 16 + r16;
            bf16x8 Bk = *(const bf16x8*)(wk + n * DM + kt * 32 + g * 8);
            bf16x8 Bv = *(const bf16x8*)(wv + n * DM + kt * 32 + g * 8);
#pragma unroll
            for (int mi = 0; mi < 4; mi++) {
                ak[mi][ni] = MFMA16(A[mi], Bk, ak[mi][ni]);
                av[mi][ni] = MFMA16(A[mi], Bv, av[mi][ni]);
            }
        }
    }
    __syncthreads();   // xs reads done before kT/vT overwrite
    // elu(k)+1, ksum partials, per-wave transposed LDS tiles kT/vT [32 feat][64 s]
    char* kT = lds + w * 8192;
    char* vT = kT + 4096;
    float ksp[2] = {0.f, 0.f};
#pragma unroll
    for (int mi = 0; mi < 4; mi++)
#pragma unroll
        for (int ni = 0; ni < 2; ni++)
#pragma unroll
            for (int j = 0; j < 4; j++) {
                float q = ak[mi][ni][j];
                float e = q > 0.f ? q + 1.f : __expf(q);
                ksp[ni] += e;
                int srow = mi * 16 + g * 4 + j, feat = ni * 16 + r16;
                int by = (feat * 128 + srow * 2) ^ ((feat & 7) << 4);
                *(short*)(kT + by) = f2bf(e);
                *(short*)(vT + by) = f2bf(av[mi][ni][j]);
            }
    __syncthreads();
    // KVT[v][d] = sum_s V[s][v] * K[s][d]  (per wave, own head)
    f32x4 kv[2][2];
#pragma unroll
    for (int vi = 0; vi < 2; vi++)
#pragma unroll
        for (int di = 0; di < 2; di++) kv[vi][di] = zz;
#pragma unroll
    for (int st = 0; st < 2; st++) {
        bf16x8 Af[2], Bf[2];
#pragma unroll
        for (int vi = 0; vi < 2; vi++) {
            int row = vi * 16 + r16;
            Af[vi] = *(const bf16x8*)(vT + ((row * 128 + (st * 32 + g * 8) * 2) ^ ((row & 7) << 4)));
            Bf[vi] = *(const bf16x8*)(kT + ((row * 128 + (st * 32 + g * 8) * 2) ^ ((row & 7) << 4)));
        }
#pragma unroll
        for (int vi = 0; vi < 2; vi++)
#pragma unroll
            for (int di = 0; di < 2; di++) kv[vi][di] = MFMA16(Af[vi], Bf[di], kv[vi][di]);
    }
    float* kvp = kv_part + ((size_t)(b * 64 + blk) * 8 + w) * 1024;
#pragma unroll
    for (int vi = 0; vi < 2; vi++)
#pragma unroll
        for (int di = 0; di < 2; di++)
#pragma unroll
            for (int j = 0; j < 4; j++) {
                int v = vi * 16 + g * 4 + j, d = di * 16 + r16;
                kvp[v * 32 + d] = kv[vi][di][j];
            }
#pragma unroll
    for (int ni = 0; ni < 2; ni++) {
        ksp[ni] += __shfl_xor(ksp[ni], 16);
        ksp[ni] += __shfl_xor(ksp[ni], 32);
    }
    if (lane < 16) {
        float* kp = ksum_part + (size_t)(b * 64 + blk) * 256 + w * 32;
#pragma unroll
        for (int ni = 0; ni < 2; ni++) kp[ni * 16 + lane] = ksp[ni];
    }
}

// ---------------- kernel A2: reduce partials ----------------
// grid 256 = b(8) x h(8) x quarter(4), 256 thr
__global__ __launch_bounds__(256) void kA2(const float* __restrict__ kv_part, const float* __restrict__ ksum_part,
                                           short* __restrict__ kvt_bf, float* __restrict__ ksum) {
    int blk = blockIdx.x, t = threadIdx.x;
    int b = blk >> 5, h = (blk >> 2) & 7, q = blk & 3;
    int e = q * 256 + t;
    float s0 = 0.f, s1 = 0.f, s2 = 0.f, s3 = 0.f;
    for (int bk = 0; bk < 64; bk += 4) {
        s0 += kv_part[((size_t)(b * 64 + bk) * 8 + h) * 1024 + e];
        s1 += kv_part[((size_t)(b * 64 + bk + 1) * 8 + h) * 1024 + e];
        s2 += kv_part[((size_t)(b * 64 + bk + 2) * 8 + h) * 1024 + e];
        s3 += kv_part[((size_t)(b * 64 + bk + 3) * 8 + h) * 1024 + e];
    }
    kvt_bf[(size_t)(b * 8 + h) * 1024 + e] = f2bf((s0 + s1) + (s2 + s3));
    if (q == 3 && t < 32) {
        float s = 0.f;
        for (int bk = 0; bk < 64; bk++)
            s += ksum_part[(size_t)(b * 64 + bk) * 256 + h * 32 + t];
        ksum[(b * 8 + h) * 32 + t] = s;
    }
}

// ---------------- kernel BC: Q proj + attend + merge + LN1 + MLP + LN2 ----------------
// grid 1024 = 8 b x 128 blocks (32 rows). 512 thr = 8 waves; wave w = head w / col-slice w.
__global__ __launch_bounds__(512, 4) void kBC(const float* __restrict__ x,
                                              const short* __restrict__ wq_bf, const short* __restrict__ wm_bf,
                                              const short* __restrict__ w1_bf, const short* __restrict__ w2_bf,
                                              const short* __restrict__ kvt_bf, const float* __restrict__ ksum,
                                              const float* __restrict__ g1, const float* __restrict__ b1,
                                              const float* __restrict__ g2, const float* __restrict__ b2,
                                              float* __restrict__ out) {
    __shared__ char lds[52224];
    // xt@0: [32][256] bf16 swz (16KB) -- holds x, later x1
    // hb@16384: [32][512] bf16 swz (32KB) -- qa ([32][256], Q then attended) aliases its first 16KB
    // red@49152: [32][8][2] f32 (2KB);  ksl@51200: [256] f32 (1KB)
    char* xt = lds;
    char* hb = lds + 16384;
    char* qa = lds + 16384;
    float* red = (float*)(lds + 49152);
    float* ksl = (float*)(lds + 51200);
    int t = threadIdx.x, lane = t & 63, w = t >> 6, r16 = lane & 15, g = lane >> 4;
    int b = blockIdx.x >> 7, lb = blockIdx.x & 127, l0 = lb * 32;
    const float* xb = x + ((size_t)b * SEQ + l0) * DM;
    // stage x tile (32 rows x 256 cols) f32->bf16 swz
#pragma unroll
    for (int i = 0; i < 2; i++) {
        int chunk = t + i * 512, row = chunk >> 5, c8 = chunk & 31;
        const float* p = xb + row * DM + c8 * 8;
        float4 f0 = *(const float4*)p, f1 = *(const float4*)(p + 4);
        int by = (row * 512 + c8 * 16) ^ ((row & 7) << 4);
        *(bf16x8*)(xt + by) = pack8(f0, f1);
    }
    if (t < 256) ksl[t] = ksum[b * 256 + t];
    __syncthreads();
    f32x4 zz = {0.f, 0.f, 0.f, 0.f};
    // ---- Q projection (wave w -> head w's 32 cols) ----
    f32x4 acc[2][2];
#pragma unroll
    for (int mi = 0; mi < 2; mi++)
#pragma unroll
        for (int ni = 0; ni < 2; ni++) acc[mi][ni] = zz;
#pragma unroll
    for (int kt = 0; kt < 8; kt++) {
        bf16x8 A[2], Bf[2];
#pragma unroll
        for (int mi = 0; mi < 2; mi++) {
            int row = mi * 16 + r16;
            A[mi] = *(const bf16x8*)(xt + ((row * 512 + (kt * 32 + g * 8) * 2) ^ ((row & 7) << 4)));
        }
#pragma unroll
        for (int ni = 0; ni < 2; ni++)
            Bf[ni] = *(const bf16x8*)(wq_bf + (w * 32 + ni * 16 + r16) * DM + kt * 32 + g * 8);
#pragma unroll
        for (int mi = 0; mi < 2; mi++)
#pragma unroll
            for (int ni = 0; ni < 2; ni++) acc[mi][ni] = MFMA16(A[mi], Bf[ni], acc[mi][ni]);
    }
    // elu+1 and Z denominators (head w fully in-wave)
    float ks0 = ksl[w * 32 + r16], ks1 = ksl[w * 32 + 16 + r16];
    float Zr[2][4];
#pragma unroll
    for (int mi = 0; mi < 2; mi++)
#pragma unroll
        for (int j = 0; j < 4; j++) {
#pragma unroll
            for (int ni = 0; ni < 2; ni++) {
                float q = acc[mi][ni][j];
                acc[mi][ni][j] = q > 0.f ? q + 1.f : __expf(q);
            }
            float d0 = acc[mi][0][j] * ks0 + acc[mi][1][j] * ks1;
#pragma unroll
            for (int m = 1; m < 16; m <<= 1) d0 += __shfl_xor(d0, m);
            Zr[mi][j] = 1.f / (d0 + 1e-6f);
        }
    // write Q (bf16, swz) -- wave-private columns
#pragma unroll
    for (int mi = 0; mi < 2; mi++)
#pragma unroll
        for (int ni = 0; ni < 2; ni++)
#pragma unroll
            for (int j = 0; j < 4; j++) {
                int row = mi * 16 + g * 4 + j, col = w * 32 + ni * 16 + r16;
                *(short*)(qa + ((row * 512 + col * 2) ^ ((row & 7) << 4))) = f2bf(acc[mi][ni][j]);
            }
    // ---- attend (wave-private: reads only own head's cols) ----
    f32x4 at[2][2];
#pragma unroll
    for (int mi = 0; mi < 2; mi++)
#pragma unroll
        for (int vi = 0; vi < 2; vi++) at[mi][vi] = zz;
    {
        bf16x8 A2[2], B2[2];
#pragma unroll
        for (int mi = 0; mi < 2; mi++) {
            int row = mi * 16 + r16, col = w * 32 + g * 8;
            A2[mi] = *(const bf16x8*)(qa + ((row * 512 + col * 2) ^ ((row & 7) << 4)));
        }
        const short* kvb = kvt_bf + (size_t)(b * 8 + w) * 1024;
#pragma unroll
        for (int vi = 0; vi < 2; vi++)
            B2[vi] = *(const bf16x8*)(kvb + (vi * 16 + r16) * 32 + g * 8);
#pragma unroll
        for (int mi = 0; mi < 2; mi++)
#pragma unroll
            for (int vi = 0; vi < 2; vi++) at[mi][vi] = MFMA16(A2[mi], B2[vi], at[mi][vi]);
    }
    // scale by Z, overwrite qa with attended (wave-private cols)
#pragma unroll
    for (int mi = 0; mi < 2; mi++)
#pragma unroll
        for (int vi = 0; vi < 2; vi++)
#pragma unroll
            for (int j = 0; j < 4; j++) {
                int row = mi * 16 + g * 4 + j, col = w * 32 + vi * 16 + r16;
                *(short*)(qa + ((row * 512 + col * 2) ^ ((row & 7) << 4))) = f2bf(at[mi][vi][j] * Zr[mi][j]);
            }
    __syncthreads();   // merge reads all columns
    // ---- merge GEMM ----
    f32x4 am[2][2];
#pragma unroll
    for (int mi = 0; mi < 2; mi++)
#pragma unroll
        for (int ni = 0; ni < 2; ni++) am[mi][ni] = zz;
#pragma unroll
    for (int kt = 0; kt < 8; kt++) {
        bf16x8 A[2], Bf[2];
#pragma unroll
        for (int mi = 0; mi < 2; mi++) {
            int row = mi * 16 + r16;
            A[mi] = *(const bf16x8*)(qa + ((row * 512 + (kt * 32 + g * 8) * 2) ^ ((row & 7) << 4)));
        }
#pragma unroll
        for (int ni = 0; ni < 2; ni++)
            Bf[ni] = *(const bf16x8*)(wm_bf + (w * 32 + ni * 16 + r16) * DM + kt * 32 + g * 8);
#pragma unroll
        for (int mi = 0; mi < 2; mi++)
#pragma unroll
            for (int ni = 0; ni < 2; ni++) am[mi][ni] = MFMA16(A[mi], Bf[ni], am[mi][ni]);
    }
    // LN1 partials
#pragma unroll
    for (int mi = 0; mi < 2; mi++)
#pragma unroll
        for (int j = 0; j < 4; j++) {
            float s = am[mi][0][j] + am[mi][1][j];
            float s2 = am[mi][0][j] * am[mi][0][j] + am[mi][1][j] * am[mi][1][j];
#pragma unroll
            for (int m = 1; m < 16; m <<= 1) { s += __shfl_xor(s, m); s2 += __shfl_xor(s2, m); }
            if (r16 == 0) { int row = mi * 16 + g * 4 + j; red[(row * 8 + w) * 2] = s; red[(row * 8 + w) * 2 + 1] = s2; }
        }
    __syncthreads();
    // x1 = x + LN1(message), overwrite xt in place (same thread, same slot)
    {
        float g1v[2], b1v[2];
#pragma unroll
        for (int ni = 0; ni < 2; ni++) { int col = w * 32 + ni * 16 + r16; g1v[ni] = g1[col]; b1v[ni] = b1[col]; }
#pragma unroll
        for (int mi = 0; mi < 2; mi++)
#pragma unroll
            for (int j = 0; j < 4; j++) {
                int row = mi * 16 + g * 4 + j;
                float mu = 0.f, ex2 = 0.f;
#pragma unroll
                for (int ww = 0; ww < 8; ww++) { mu += red[(row * 8 + ww) * 2]; ex2 += red[(row * 8 + ww) * 2 + 1]; }
                mu *= (1.f / DM); ex2 *= (1.f / DM);
                float rstd = rsqrtf(ex2 - mu * mu + 1e-5f);
#pragma unroll
                for (int ni = 0; ni < 2; ni++) {
                    int col = w * 32 + ni * 16 + r16;
                    int by = (row * 512 + col * 2) ^ ((row & 7) << 4);
                    float xv = bf2f(*(const short*)(xt + by));
                    *(short*)(xt + by) = f2bf(xv + (am[mi][ni][j] - mu) * rstd * g1v[ni] + b1v[ni]);
                }
            }
    }
    __syncthreads();
    // ---- MLP GEMM1: h = relu(x1 @ w1^T), wave w -> cols [w*64, w*64+64) ----
    f32x4 a1[2][4];
#pragma unroll
    for (int mi = 0; mi < 2; mi++)
#pragma unroll
        for (int ni = 0; ni < 4; ni++) a1[mi][ni] = zz;
#pragma unroll
    for (int kt = 0; kt < 8; kt++) {
        bf16x8 A[2], Bf[4];
#pragma unroll
        for (int mi = 0; mi < 2; mi++) {
            int row = mi * 16 + r16;
            A[mi] = *(const bf16x8*)(xt + ((row * 512 + (kt * 32 + g * 8) * 2) ^ ((row & 7) << 4)));
        }
#pragma unroll
        for (int ni = 0; ni < 4; ni++)
            Bf[ni] = *(const bf16x8*)(w1_bf + (w * 64 + ni * 16 + r16) * DM + kt * 32 + g * 8);
#pragma unroll
        for (int mi = 0; mi < 2; mi++)
#pragma unroll
            for (int ni = 0; ni < 4; ni++) a1[mi][ni] = MFMA16(A[mi], Bf[ni], a1[mi][ni]);
    }
    // relu + write h [32][512] bf16 swz
#pragma unroll
    for (int mi = 0; mi < 2; mi++)
#pragma unroll
        for (int ni = 0; ni < 4; ni++)
#pragma unroll
            for (int j = 0; j < 4; j++) {
                float hv = a1[mi][ni][j]; hv = hv > 0.f ? hv : 0.f;
                int row = mi * 16 + g * 4 + j, col = w * 64 + ni * 16 + r16;
                *(short*)(hb + ((row * 1024 + col * 2) ^ ((row & 7) << 4))) = f2bf(hv);
            }
    __syncthreads();
    // ---- MLP GEMM2: y = h @ w2^T (K=512), wave w -> cols [w*32, w*32+32) ----
    f32x4 a2[2][2];
#pragma unroll
    for (int mi = 0; mi < 2; mi++)
#pragma unroll
        for (int ni = 0; ni < 2; ni++) a2[mi][ni] = zz;
#pragma unroll
    for (int kt = 0; kt < 16; kt++) {
        bf16x8 A[2], Bf[2];
#pragma unroll
        for (int mi = 0; mi < 2; mi++) {
            int row = mi * 16 + r16;
            A[mi] = *(const bf16x8*)(hb + ((row * 1024 + (kt * 32 + g * 8) * 2) ^ ((row & 7) << 4)));
        }
#pragma unroll
        for (int ni = 0; ni < 2; ni++)
            Bf[ni] = *(const bf16x8*)(w2_bf + (w * 32 + ni * 16 + r16) * 512 + kt * 32 + g * 8);
#pragma unroll
        for (int mi = 0; mi < 2; mi++)
#pragma unroll
            for (int ni = 0; ni < 2; ni++) a2[mi][ni] = MFMA16(A[mi], Bf[ni], a2[mi][ni]);
    }
    // LN2 partials
#pragma unroll
    for (int mi = 0; mi < 2; mi++)
#pragma unroll
        for (int j = 0; j < 4; j++) {
            float s = a2[mi][0][j] + a2[mi][1][j];
            float s2 = a2[mi][0][j] * a2[mi][0][j] + a2[mi][1][j] * a2[mi][1][j];
#pragma unroll
            for (int m = 1; m < 16; m <<= 1) { s += __shfl_xor(s, m); s2 += __shfl_xor(s2, m); }
            if (r16 == 0) { int row = mi * 16 + g * 4 + j; red[(row * 8 + w) * 2] = s; red[(row * 8 + w) * 2 + 1] = s2; }
        }
    __syncthreads();
    // out = x1 + LN2(y), direct stores (64B-contiguous runs per 16 lanes)
    {
        float g2v[2], b2v[2];
#pragma unroll
        for (int ni = 0; ni < 2; ni++) { int col = w * 32 + ni * 16 + r16; g2v[ni] = g2[col]; b2v[ni] = b2[col]; }
        float* op = out + ((size_t)b * SEQ + l0) * DM;
#pragma unroll
        for (int mi = 0; mi < 2; mi++)
#pragma unroll
            for (int j = 0; j < 4; j++) {
                int row = mi * 16 + g * 4 + j;
                float mu = 0.f, ex2 = 0.f;
#pragma unroll
                for (int ww = 0; ww < 8; ww++) { mu += red[(row * 8 + ww) * 2]; ex2 += red[(row * 8 + ww) * 2 + 1]; }
                mu *= (1.f / DM); ex2 *= (1.f / DM);
                float rstd = rsqrtf(ex2 - mu * mu + 1e-5f);
#pragma unroll
                for (int ni = 0; ni < 2; ni++) {
                    int col = w * 32 + ni * 16 + r16;
                    float xv = bf2f(*(const short*)(xt + ((row * 512 + col * 2) ^ ((row & 7) << 4))));
                    op[row * DM + col] = xv + (a2[mi][ni][j] - mu) * rstd * g2v[ni] + b2v[ni];
                }
            }
    }
}

extern "C" void kernel_launch(void* const* d_in, const int* in_sizes, int n_in,
                              void* d_out, int out_size, void* d_ws, size_t ws_size,
                              hipStream_t stream) {
    const float* x   = (const float*)d_in[0];
    const float* src = (const float*)d_in[1];
    const float* wq  = (const float*)d_in[2];
    const float* wk  = (const float*)d_in[3];
    const float* wv  = (const float*)d_in[4];
    const float* wm  = (const float*)d_in[5];
    const float* w1  = (const float*)d_in[6];
    const float* w2  = (const float*)d_in[7];
    const float* g1  = (const float*)d_in[8];
    const float* b1  = (const float*)d_in[9];
    const float* g2  = (const float*)d_in[10];
    const float* b2  = (const float*)d_in[11];
    float* out = (float*)d_out;

    char* ws = (char*)d_ws;
    short* w_bf      = (short*)ws;                    // 1,048,576 B
    short* kvt_bf    = (short*)(ws + 1048576);        //   131,072 B
    float* ksum      = (float*)(ws + 1179648);        //     8,192 B
    float* kv_part   = (float*)(ws + 1187840);        // 16,777,216 B
    float* ksum_part = (float*)(ws + 17965056);       //    524,288 B

    kWconv<<<256, 256, 0, stream>>>(wq, wk, wv, wm, w1, w2, w_bf);
    kA<<<512, 512, 0, stream>>>(src, w_bf + 65536, w_bf + 131072, kv_part, ksum_part);
    kA2<<<256, 256, 0, stream>>>(kv_part, ksum_part, kvt_bf, ksum);
    kBC<<<1024, 512, 0, stream>>>(x, w_bf, w_bf + 196608, w_bf + 262144, w_bf + 393216,
                                  kvt_bf, ksum, g1, b1, g2, b2, out);
}